// Round 1
// baseline (229.935 us; speedup 1.0000x reference)
//
#include <hip/hip_runtime.h>
#include <hip/hip_bf16.h>
#include <stdint.h>

#define T_TOK 8192
#define D_IN  1024
#define N_EXP 8
#define D_OUT 1024

// 256x256 tile geometry for moe_gemm
#define BM2 256
#define BN2 256
#define BK2 32
#define NT2 32   // K steps = 1024/32

typedef short s8v __attribute__((ext_vector_type(8)));
typedef float f4v __attribute__((ext_vector_type(4)));
typedef unsigned short ushort_t;

__device__ __forceinline__ ushort_t f2bf(float f) {
    uint32_t u = __float_as_uint(f);
    uint32_t r = (u + 0x7fffu + ((u >> 16) & 1u)) >> 16;
    return (ushort_t)r;
}

__device__ __forceinline__ float bf2f(ushort_t u) {
    return __uint_as_float(((uint32_t)u) << 16);
}

__device__ __forceinline__ void async_copy16(const void* g, void* lds) {
    __builtin_amdgcn_global_load_lds(
        (const __attribute__((address_space(1))) unsigned int*)g,
        (__attribute__((address_space(3))) unsigned int*)lds,
        16, 0, 0);
}

// ------- fused prep: [0,T_TOK) logits+x-cast; [T_TOK,..) We transpose -------
__global__ __launch_bounds__(256)
void prep_kernel(const float* __restrict__ x,
                 const float* __restrict__ Wr,
                 const float* __restrict__ br,
                 const float* __restrict__ We,
                 ushort_t* __restrict__ xb,
                 ushort_t* __restrict__ Webt,
                 float* __restrict__ logits,
                 int* __restrict__ cnt,
                 float* __restrict__ psum) {
    __shared__ float red[4][N_EXP];
    __shared__ float tile[64][65];
    int bid = blockIdx.x;
    int tid = threadIdx.x;

    if (bid < T_TOK) {
        int t    = bid;
        int lane = tid & 63;
        int wv   = tid >> 6;

        float4 xv = *(const float4*)(x + (size_t)t * D_IN + tid * 4);
        ushort4 u;
        u.x = f2bf(xv.x); u.y = f2bf(xv.y);
        u.z = f2bf(xv.z); u.w = f2bf(xv.w);
        *(ushort4*)(xb + (size_t)t * D_IN + tid * 4) = u;

        const float* wr = Wr + (size_t)tid * 4 * N_EXP;
        float acc[N_EXP];
#pragma unroll
        for (int e = 0; e < N_EXP; ++e) acc[e] = 0.f;
#pragma unroll
        for (int j = 0; j < 4; ++j) {
            float xj = (j == 0) ? xv.x : (j == 1) ? xv.y : (j == 2) ? xv.z : xv.w;
#pragma unroll
            for (int e = 0; e < N_EXP; ++e)
                acc[e] += xj * wr[j * N_EXP + e];
        }
#pragma unroll
        for (int e = 0; e < N_EXP; ++e) {
#pragma unroll
            for (int off = 32; off; off >>= 1)
                acc[e] += __shfl_xor(acc[e], off, 64);
        }
        if (lane == 0) {
#pragma unroll
            for (int e = 0; e < N_EXP; ++e) red[wv][e] = acc[e];
        }
        __syncthreads();
        if (tid < N_EXP)
            logits[(size_t)t * N_EXP + tid] =
                red[0][tid] + red[1][tid] + red[2][tid] + red[3][tid] + br[tid];
    } else {
        int b  = bid - T_TOK;          // 0..2047
        int e  = b >> 8;
        int k0 = ((b >> 4) & 15) * 64; // D index
        int h0 = (b & 15) * 64;        // DOUT index
        if (b == 0 && tid < N_EXP) { cnt[tid] = 0; psum[tid] = 0.f; }

        const float* src = We + ((size_t)e * D_IN + k0) * D_OUT + h0;
#pragma unroll
        for (int it = 0; it < 4; ++it) {
            int lin = it * 256 + tid;
            int r = lin >> 4;
            int c4 = (lin & 15) * 4;
            float4 v = *(const float4*)(src + (size_t)r * D_OUT + c4);
            tile[r][c4]     = v.x; tile[r][c4 + 1] = v.y;
            tile[r][c4 + 2] = v.z; tile[r][c4 + 3] = v.w;
        }
        __syncthreads();
        ushort_t* dst = Webt + ((size_t)e * D_OUT + h0) * D_IN + k0;
#pragma unroll
        for (int it = 0; it < 4; ++it) {
            int lin = it * 256 + tid;
            int h = lin >> 4;
            int k4 = (lin & 15) * 4;
            ushort4 u;
            u.x = f2bf(tile[k4][h]);     u.y = f2bf(tile[k4 + 1][h]);
            u.z = f2bf(tile[k4 + 2][h]); u.w = f2bf(tile[k4 + 3][h]);
            *(ushort4*)(dst + (size_t)h * D_IN + k4) = u;
        }
    }
}

// ------- route: softmax + top2 + expert lists (1 token per thread) ----------
__global__ __launch_bounds__(256)
void route_kernel(const float* __restrict__ logits,
                  float* __restrict__ wslot,
                  int* __restrict__ entries,
                  int* __restrict__ cnt,
                  float* __restrict__ psum) {
    __shared__ int lcnt[N_EXP];
    __shared__ int gbase[N_EXP];
    __shared__ float lps[N_EXP];
    int tid  = threadIdx.x;
    int lane = tid & 63;
    int t    = blockIdx.x * 256 + tid;
    if (tid < N_EXP) { lcnt[tid] = 0; lps[tid] = 0.f; }
    __syncthreads();

    float p[N_EXP];
    float4 l0 = *(const float4*)(logits + (size_t)t * N_EXP);
    float4 l1 = *(const float4*)(logits + (size_t)t * N_EXP + 4);
    p[0] = l0.x; p[1] = l0.y; p[2] = l0.z; p[3] = l0.w;
    p[4] = l1.x; p[5] = l1.y; p[6] = l1.z; p[7] = l1.w;

    float m = p[0];
#pragma unroll
    for (int e = 1; e < N_EXP; ++e) m = fmaxf(m, p[e]);
    float Z = 0.f;
#pragma unroll
    for (int e = 0; e < N_EXP; ++e) { p[e] = expf(p[e] - m); Z += p[e]; }
    float invZ = 1.f / Z;
#pragma unroll
    for (int e = 0; e < N_EXP; ++e) p[e] *= invZ;

#pragma unroll
    for (int e = 0; e < N_EXP; ++e) {
        float v = p[e];
#pragma unroll
        for (int off = 32; off; off >>= 1) v += __shfl_xor(v, off, 64);
        if (lane == 0) atomicAdd(&lps[e], v);
    }

    int i0 = 0; float b0 = p[0];
#pragma unroll
    for (int e = 1; e < N_EXP; ++e) if (p[e] > b0) { b0 = p[e]; i0 = e; }
    int i1 = (i0 == 0) ? 1 : 0; float b1 = p[i1];
#pragma unroll
    for (int e = 0; e < N_EXP; ++e)
        if (e != i0 && p[e] > b1) { b1 = p[e]; i1 = e; }
    float denom = b0 + b1 + 1e-9f;
    float2 w01; w01.x = b0 / denom; w01.y = b1 / denom;
    *(float2*)(wslot + 2 * t) = w01;

    int lpos0 = atomicAdd(&lcnt[i0], 1);
    int lpos1 = atomicAdd(&lcnt[i1], 1);
    __syncthreads();
    if (tid < N_EXP) {
        gbase[tid] = atomicAdd(&cnt[tid], lcnt[tid]);
        atomicAdd(&psum[tid], lps[tid]);
    }
    __syncthreads();
    entries[i0 * T_TOK + gbase[i0] + lpos0] = 2 * t;
    entries[i1 * T_TOK + gbase[i1] + lpos1] = 2 * t + 1;
}

// ------- grouped GEMM, 256x256 / 8 waves, BK=32, 4-buffer LDS ring,
//         phase-split schedule (T3) with counted vmcnt(8) (T4), setprio
//         around MFMA clusters (T5), chunk-XOR swizzle (T2), XCD-pinned
//         experts (T1), LDS-staged coalesced bf16 epilogue ------------------

#define MF4(MI, AV)                                                            \
    acc[MI][0] = __builtin_amdgcn_mfma_f32_16x16x32_bf16(AV, b0_, acc[MI][0], 0, 0, 0); \
    acc[MI][1] = __builtin_amdgcn_mfma_f32_16x16x32_bf16(AV, b1_, acc[MI][1], 0, 0, 0); \
    acc[MI][2] = __builtin_amdgcn_mfma_f32_16x16x32_bf16(AV, b2_, acc[MI][2], 0, 0, 0); \
    acc[MI][3] = __builtin_amdgcn_mfma_f32_16x16x32_bf16(AV, b3_, acc[MI][3], 0, 0, 0);

// One K-step (BK=32) in 2 phases of 16 MFMA each.
// BUFC must equal (T)&3 at every expansion site (checked by construction).
// Stages tile T+3 into ring slot (BUFC+3)&3 (last read at step T-1 -> free).
// VMN: counted vmcnt at end of step; -1 = none.
#define KSTEP(T, BUFC, DOSTAGE, VMN)                                           \
    do {                                                                       \
        const char* ab_ = smem + (BUFC) * 32768;                               \
        s8v a0_ = *(const s8v*)(ab_ + aoff[0]);                                \
        s8v a1_ = *(const s8v*)(ab_ + aoff[1]);                                \
        s8v a2_ = *(const s8v*)(ab_ + aoff[2]);                                \
        s8v a3_ = *(const s8v*)(ab_ + aoff[3]);                                \
        s8v b0_ = *(const s8v*)(ab_ + boff[0]);                                \
        s8v b1_ = *(const s8v*)(ab_ + boff[1]);                                \
        s8v b2_ = *(const s8v*)(ab_ + boff[2]);                                \
        s8v b3_ = *(const s8v*)(ab_ + boff[3]);                                \
        if (DOSTAGE) {                                                         \
            char* sb_ = smem + (((BUFC) + 3) & 3) * 32768;                     \
            int kk_ = ((T) + 3) * BK2;                                         \
            async_copy16(gA0 + kk_, sb_ + ldsOff);                             \
            async_copy16(gA1 + kk_, sb_ + 8192 + ldsOff);                      \
        }                                                                      \
        asm volatile("s_barrier" ::: "memory");                                \
        __builtin_amdgcn_s_setprio(1);                                         \
        MF4(0, a0_) MF4(1, a1_) MF4(2, a2_) MF4(3, a3_)                        \
        __builtin_amdgcn_s_setprio(0);                                         \
        asm volatile("s_barrier" ::: "memory");                                \
        s8v a4_ = *(const s8v*)(ab_ + aoff[4]);                                \
        s8v a5_ = *(const s8v*)(ab_ + aoff[5]);                                \
        s8v a6_ = *(const s8v*)(ab_ + aoff[6]);                                \
        s8v a7_ = *(const s8v*)(ab_ + aoff[7]);                                \
        if (DOSTAGE) {                                                         \
            char* sb_ = smem + (((BUFC) + 3) & 3) * 32768;                     \
            int kk_ = ((T) + 3) * BK2;                                         \
            async_copy16(gB0 + kk_, sb_ + 16384 + ldsOff);                     \
            async_copy16(gB1 + kk_, sb_ + 24576 + ldsOff);                     \
        }                                                                      \
        if ((VMN) == 8)                                                        \
            asm volatile("s_waitcnt vmcnt(8)" ::: "memory");                   \
        else if ((VMN) == 4)                                                   \
            asm volatile("s_waitcnt vmcnt(4)" ::: "memory");                   \
        else if ((VMN) == 0)                                                   \
            asm volatile("s_waitcnt vmcnt(0)" ::: "memory");                   \
        asm volatile("s_barrier" ::: "memory");                                \
        __builtin_amdgcn_s_setprio(1);                                         \
        MF4(4, a4_) MF4(5, a5_) MF4(6, a6_) MF4(7, a7_)                        \
        __builtin_amdgcn_s_setprio(0);                                         \
        asm volatile("s_barrier" ::: "memory");                                \
    } while (0)

__global__ __launch_bounds__(512, 2)
void moe_gemm(const ushort_t* __restrict__ xb,
              const ushort_t* __restrict__ Webt,
              const float* __restrict__ be,
              const int* __restrict__ entries,
              const int* __restrict__ cnt,
              const float* __restrict__ wslot,
              ushort_t* __restrict__ yslot) {
    int idx  = blockIdx.x;
    int e    = idx & 7;          // XCD-affinity: expert e -> XCD e
    int rest = idx >> 3;
    int bn   = rest & 3;         // 4 col tiles of 256
    int bm   = rest >> 2;        // up to 32 row tiles of 256
    int cnte = cnt[e];
    if (bm * BM2 >= cnte) return;

    // 4-slot ring: per slot A[256][32]bf16 (16KB) + B[256][32]bf16 (16KB)
    __shared__ __attribute__((aligned(16))) char smem[4 * 32768];

    int tid    = threadIdx.x;
    int lane   = tid & 63;
    int wv     = tid >> 6;        // 0..7, 2(M) x 4(N)
    int lane15 = lane & 15;
    int quad   = lane >> 4;
    int wm = (wv >> 2) * 128;     // wave row base within tile
    int wn = (wv & 3) * 64;       // wave col base within tile

    // staging addresses (16B chunk XOR-swizzle on the GLOBAL source; LDS
    // dest stays linear as required by global_load_lds)
    int rA  = tid >> 2;                         // 0..127
    int csw = (tid & 3) ^ ((rA >> 1) & 3);
    const int* epe = entries + e * T_TOK;
    int r0 = bm * BM2 + rA;
    int r1 = r0 + 128;
    int c0 = r0 < cnte ? r0 : cnte - 1;
    int c1 = r1 < cnte ? r1 : cnte - 1;
    int tok0 = epe[c0] >> 1;
    int tok1 = epe[c1] >> 1;
    const ushort_t* gA0 = xb + (size_t)tok0 * D_IN + csw * 8;
    const ushort_t* gA1 = xb + (size_t)tok1 * D_IN + csw * 8;
    const ushort_t* WB  = Webt + (size_t)e * D_IN * D_OUT + csw * 8;
    const ushort_t* gB0 = WB + (size_t)(bn * BN2 + rA) * D_IN;
    const ushort_t* gB1 = WB + (size_t)(bn * BN2 + rA + 128) * D_IN;
    int ldsOff = tid * 16;

    // fragment read offsets (mirror the XOR swizzle)
    int aoff[8], boff[4];
#pragma unroll
    for (int mi = 0; mi < 8; ++mi) {
        int m = wm + mi * 16 + lane15;
        aoff[mi] = m * 64 + (quad ^ ((m >> 1) & 3)) * 16;
    }
#pragma unroll
    for (int ni = 0; ni < 4; ++ni) {
        int n = wn + ni * 16 + lane15;
        boff[ni] = 16384 + n * 64 + (quad ^ ((n >> 1) & 3)) * 16;
    }

    f4v acc[8][4];
#pragma unroll
    for (int mi = 0; mi < 8; ++mi)
#pragma unroll
        for (int ni = 0; ni < 4; ++ni)
            acc[mi][ni] = (f4v){0.f, 0.f, 0.f, 0.f};

    // prologue: tiles 0,1,2 in flight (12 loads); wait leaves 8 outstanding
#pragma unroll
    for (int pt = 0; pt < 3; ++pt) {
        char* sb = smem + pt * 32768;
        int kk = pt * BK2;
        async_copy16(gA0 + kk, sb + ldsOff);
        async_copy16(gA1 + kk, sb + 8192 + ldsOff);
        async_copy16(gB0 + kk, sb + 16384 + ldsOff);
        async_copy16(gB1 + kk, sb + 24576 + ldsOff);
    }
    asm volatile("s_waitcnt vmcnt(8)\n\ts_barrier" ::: "memory");

    // steady state: while computing tile t, stage tile t+3; end-of-step
    // vmcnt(8) retires tile t+1 (2 tiles always in flight, never drain to 0)
    for (int tt = 0; tt < 28; tt += 4) {
        KSTEP(tt + 0, 0, 1, 8);
        KSTEP(tt + 1, 1, 1, 8);
        KSTEP(tt + 2, 2, 1, 8);
        KSTEP(tt + 3, 3, 1, 8);
    }
    KSTEP(28, 0, 1, 8);   // stages tile 31
    KSTEP(29, 1, 0, 4);
    KSTEP(30, 2, 0, 0);
    KSTEP(31, 3, 0, -1);

    // ---- epilogue: scale+bias, stage 128-row halves in LDS (aliased),
    //      coalesced scattered bf16 stores
    __syncthreads();   // drain everything before smem reuse
    ushort_t (*ot)[264] = (ushort_t(*)[264])smem;  // 128 x 264 x 2B = 67.5KB
    float bev[4];
#pragma unroll
    for (int ni = 0; ni < 4; ++ni)
        bev[ni] = be[e * D_OUT + bn * BN2 + wn + ni * 16 + lane15];

#pragma unroll
    for (int half = 0; half < 2; ++half) {
        if ((wv >> 2) == half) {
#pragma unroll
            for (int mi = 0; mi < 8; ++mi) {
#pragma unroll
                for (int r = 0; r < 4; ++r) {
                    int lrow = mi * 16 + quad * 4 + r;
                    int grow = bm * BM2 + half * 128 + lrow;
                    int cr   = grow < cnte ? grow : cnte - 1;
                    float w  = grow < cnte ? wslot[epe[cr]] : 0.f;
#pragma unroll
                    for (int ni = 0; ni < 4; ++ni)
                        ot[lrow][wn + ni * 16 + lane15] =
                            f2bf(w * (acc[mi][ni][r] + bev[ni]));
                }
            }
        }
        __syncthreads();
        {
            int row = tid >> 2;
            int q4  = tid & 3;
            int grow = bm * BM2 + half * 128 + row;
            if (grow < cnte) {
                int ent = epe[grow];
                ushort_t* dst = yslot + (size_t)ent * D_OUT + bn * BN2;
                const ushort_t* srcr = ot[row];
#pragma unroll
                for (int j = 0; j < 8; ++j) {
                    int off = (j * 4 + q4) * 8;  // interleaved 16B chunks
                    *(s8v*)(dst + off) = *(const s8v*)(srcr + off);
                }
            }
        }
        __syncthreads();
    }
}

// ------- combine (+ fused aux): y[t] = ys[2t] + ys[2t+1] --------------------
__global__ void combine_kernel(const ushort_t* __restrict__ yslot,
                               const float* __restrict__ psum,
                               const int* __restrict__ cnt,
                               float* __restrict__ out) {
    size_t i = ((size_t)blockIdx.x * 256 + threadIdx.x) * 4;
    size_t t = i >> 10;
    size_t h = i & 1023;
    const ushort_t* p0 = yslot + (2 * t) * D_OUT + h;
    ushort4 a = *(const ushort4*)p0;
    ushort4 b = *(const ushort4*)(p0 + D_OUT);
    float4 o;
    o.x = bf2f(a.x) + bf2f(b.x);
    o.y = bf2f(a.y) + bf2f(b.y);
    o.z = bf2f(a.z) + bf2f(b.z);
    o.w = bf2f(a.w) + bf2f(b.w);
    *(float4*)(out + i) = o;
    if (i == 0) {
        float s = 0.f;
#pragma unroll
        for (int e = 0; e < N_EXP; ++e)
            s += (psum[e] / (float)T_TOK) * ((float)cnt[e] / (float)(T_TOK * 2));
        out[(size_t)T_TOK * D_OUT] = (float)N_EXP * s;
    }
}

extern "C" void kernel_launch(void* const* d_in, const int* in_sizes, int n_in,
                              void* d_out, int out_size, void* d_ws, size_t ws_size,
                              hipStream_t stream) {
    const float* x  = (const float*)d_in[0];
    const float* Wr = (const float*)d_in[1];
    const float* br = (const float*)d_in[2];
    const float* We = (const float*)d_in[3];
    const float* be = (const float*)d_in[4];
    float* out = (float*)d_out;

    char* ws = (char*)d_ws;
    ushort_t* xb      = (ushort_t*)(ws);                    // 16 MiB
    ushort_t* Webt    = (ushort_t*)(ws + 16777216);         // 16 MiB
    ushort_t* yslot   = (ushort_t*)(ws + 33554432);         // 32 MiB (bf16)
    int*      entries = (int*)(ws + 67108864);              // 256 KiB
    float*    wslot   = (float*)(ws + 67371008);            // 64 KiB
    float*    logits  = (float*)(ws + 67436544);            // 256 KiB
    float*    psum    = (float*)(ws + 67698688);            // 32 B
    int*      cnt     = (int*)(ws + 67698720);              // 32 B

    hipLaunchKernelGGL(prep_kernel, dim3(T_TOK + 2048), dim3(256), 0, stream,
                       x, Wr, br, We, xb, Webt, logits, cnt, psum);
    hipLaunchKernelGGL(route_kernel, dim3(32), dim3(256), 0, stream,
                       logits, wslot, entries, cnt, psum);
    hipLaunchKernelGGL(moe_gemm, dim3(1024), dim3(512), 0, stream,
                       xb, Webt, be, entries, cnt, wslot, yslot);
    hipLaunchKernelGGL(combine_kernel, dim3(8192), dim3(256), 0, stream,
                       yslot, psum, cnt, out);
}

// Round 2
// 212.817 us; speedup vs baseline: 1.0804x; 1.0804x over previous
//
#include <hip/hip_runtime.h>
#include <hip/hip_bf16.h>
#include <stdint.h>

#define T_TOK 8192
#define D_IN  1024
#define N_EXP 8
#define D_OUT 1024

// 128x256 tile geometry for moe_gemm (2 blocks/CU co-residency)
#define BM2 128
#define BN2 256
#define BK2 32
#define NT2 32   // K steps = 1024/32
#define SLOT 24576  // A 8KB + B 16KB per ring slot

typedef short s8v __attribute__((ext_vector_type(8)));
typedef float f4v __attribute__((ext_vector_type(4)));
typedef unsigned short ushort_t;

__device__ __forceinline__ ushort_t f2bf(float f) {
    uint32_t u = __float_as_uint(f);
    uint32_t r = (u + 0x7fffu + ((u >> 16) & 1u)) >> 16;
    return (ushort_t)r;
}

__device__ __forceinline__ float bf2f(ushort_t u) {
    return __uint_as_float(((uint32_t)u) << 16);
}

__device__ __forceinline__ void async_copy16(const void* g, void* lds) {
    __builtin_amdgcn_global_load_lds(
        (const __attribute__((address_space(1))) unsigned int*)g,
        (__attribute__((address_space(3))) unsigned int*)lds,
        16, 0, 0);
}

// Fenced pipeline barrier: memory clobber stops the compiler from moving any
// LDS/global op across it; lgkmcnt(0) guarantees own ds_reads completed
// before passing the barrier (inter-wave buffer-reuse safety).
#define PIPE_BARRIER_VM6() \
    asm volatile("s_waitcnt vmcnt(6) lgkmcnt(0)\n\ts_barrier" ::: "memory")
#define PIPE_BARRIER_VM0() \
    asm volatile("s_waitcnt vmcnt(0) lgkmcnt(0)\n\ts_barrier" ::: "memory")

// ------- fused prep: [0,T_TOK) logits+x-cast; [T_TOK,..) We transpose -------
__global__ __launch_bounds__(256)
void prep_kernel(const float* __restrict__ x,
                 const float* __restrict__ Wr,
                 const float* __restrict__ br,
                 const float* __restrict__ We,
                 ushort_t* __restrict__ xb,
                 ushort_t* __restrict__ Webt,
                 float* __restrict__ logits,
                 int* __restrict__ cnt,
                 float* __restrict__ psum) {
    __shared__ float red[4][N_EXP];
    __shared__ float tile[64][65];
    int bid = blockIdx.x;
    int tid = threadIdx.x;

    if (bid < T_TOK) {
        int t    = bid;
        int lane = tid & 63;
        int wv   = tid >> 6;

        float4 xv = *(const float4*)(x + (size_t)t * D_IN + tid * 4);
        ushort4 u;
        u.x = f2bf(xv.x); u.y = f2bf(xv.y);
        u.z = f2bf(xv.z); u.w = f2bf(xv.w);
        *(ushort4*)(xb + (size_t)t * D_IN + tid * 4) = u;

        const float* wr = Wr + (size_t)tid * 4 * N_EXP;
        float acc[N_EXP];
#pragma unroll
        for (int e = 0; e < N_EXP; ++e) acc[e] = 0.f;
#pragma unroll
        for (int j = 0; j < 4; ++j) {
            float xj = (j == 0) ? xv.x : (j == 1) ? xv.y : (j == 2) ? xv.z : xv.w;
#pragma unroll
            for (int e = 0; e < N_EXP; ++e)
                acc[e] += xj * wr[j * N_EXP + e];
        }
#pragma unroll
        for (int e = 0; e < N_EXP; ++e) {
#pragma unroll
            for (int off = 32; off; off >>= 1)
                acc[e] += __shfl_xor(acc[e], off, 64);
        }
        if (lane == 0) {
#pragma unroll
            for (int e = 0; e < N_EXP; ++e) red[wv][e] = acc[e];
        }
        __syncthreads();
        if (tid < N_EXP)
            logits[(size_t)t * N_EXP + tid] =
                red[0][tid] + red[1][tid] + red[2][tid] + red[3][tid] + br[tid];
    } else {
        int b  = bid - T_TOK;          // 0..2047
        int e  = b >> 8;
        int k0 = ((b >> 4) & 15) * 64; // D index
        int h0 = (b & 15) * 64;        // DOUT index
        if (b == 0 && tid < N_EXP) { cnt[tid] = 0; psum[tid] = 0.f; }

        const float* src = We + ((size_t)e * D_IN + k0) * D_OUT + h0;
#pragma unroll
        for (int it = 0; it < 4; ++it) {
            int lin = it * 256 + tid;
            int r = lin >> 4;
            int c4 = (lin & 15) * 4;
            float4 v = *(const float4*)(src + (size_t)r * D_OUT + c4);
            tile[r][c4]     = v.x; tile[r][c4 + 1] = v.y;
            tile[r][c4 + 2] = v.z; tile[r][c4 + 3] = v.w;
        }
        __syncthreads();
        ushort_t* dst = Webt + ((size_t)e * D_OUT + h0) * D_IN + k0;
#pragma unroll
        for (int it = 0; it < 4; ++it) {
            int lin = it * 256 + tid;
            int h = lin >> 4;
            int k4 = (lin & 15) * 4;
            ushort4 u;
            u.x = f2bf(tile[k4][h]);     u.y = f2bf(tile[k4 + 1][h]);
            u.z = f2bf(tile[k4 + 2][h]); u.w = f2bf(tile[k4 + 3][h]);
            *(ushort4*)(dst + (size_t)h * D_IN + k4) = u;
        }
    }
}

// ------- route: softmax + top2 + expert lists (1 token per thread) ----------
__global__ __launch_bounds__(256)
void route_kernel(const float* __restrict__ logits,
                  float* __restrict__ wslot,
                  int* __restrict__ entries,
                  int* __restrict__ cnt,
                  float* __restrict__ psum) {
    __shared__ int lcnt[N_EXP];
    __shared__ int gbase[N_EXP];
    __shared__ float lps[N_EXP];
    int tid  = threadIdx.x;
    int lane = tid & 63;
    int t    = blockIdx.x * 256 + tid;
    if (tid < N_EXP) { lcnt[tid] = 0; lps[tid] = 0.f; }
    __syncthreads();

    float p[N_EXP];
    float4 l0 = *(const float4*)(logits + (size_t)t * N_EXP);
    float4 l1 = *(const float4*)(logits + (size_t)t * N_EXP + 4);
    p[0] = l0.x; p[1] = l0.y; p[2] = l0.z; p[3] = l0.w;
    p[4] = l1.x; p[5] = l1.y; p[6] = l1.z; p[7] = l1.w;

    float m = p[0];
#pragma unroll
    for (int e = 1; e < N_EXP; ++e) m = fmaxf(m, p[e]);
    float Z = 0.f;
#pragma unroll
    for (int e = 0; e < N_EXP; ++e) { p[e] = expf(p[e] - m); Z += p[e]; }
    float invZ = 1.f / Z;
#pragma unroll
    for (int e = 0; e < N_EXP; ++e) p[e] *= invZ;

#pragma unroll
    for (int e = 0; e < N_EXP; ++e) {
        float v = p[e];
#pragma unroll
        for (int off = 32; off; off >>= 1) v += __shfl_xor(v, off, 64);
        if (lane == 0) atomicAdd(&lps[e], v);
    }

    int i0 = 0; float b0 = p[0];
#pragma unroll
    for (int e = 1; e < N_EXP; ++e) if (p[e] > b0) { b0 = p[e]; i0 = e; }
    int i1 = (i0 == 0) ? 1 : 0; float b1 = p[i1];
#pragma unroll
    for (int e = 0; e < N_EXP; ++e)
        if (e != i0 && p[e] > b1) { b1 = p[e]; i1 = e; }
    float denom = b0 + b1 + 1e-9f;
    float2 w01; w01.x = b0 / denom; w01.y = b1 / denom;
    *(float2*)(wslot + 2 * t) = w01;

    int lpos0 = atomicAdd(&lcnt[i0], 1);
    int lpos1 = atomicAdd(&lcnt[i1], 1);
    __syncthreads();
    if (tid < N_EXP) {
        gbase[tid] = atomicAdd(&cnt[tid], lcnt[tid]);
        atomicAdd(&psum[tid], lps[tid]);
    }
    __syncthreads();
    entries[i0 * T_TOK + gbase[i0] + lpos0] = 2 * t;
    entries[i1 * T_TOK + gbase[i1] + lpos1] = 2 * t + 1;
}

// ------- grouped GEMM, 128x256, 4 waves, 3-slot LDS ring (72KB ->
//         2 blocks/CU co-residency), counted vmcnt(6) pipeline, chunk-XOR
//         swizzle, XCD-pinned experts, LDS-staged coalesced bf16 epilogue ----
__global__ __launch_bounds__(256, 2)
void moe_gemm(const ushort_t* __restrict__ xb,
              const ushort_t* __restrict__ Webt,
              const float* __restrict__ be,
              const int* __restrict__ entries,
              const int* __restrict__ cnt,
              const float* __restrict__ wslot,
              ushort_t* __restrict__ yslot) {
    int idx  = blockIdx.x;
    int e    = idx & 7;          // XCD-affinity: expert e -> XCD e
    int rest = idx >> 3;
    int bn   = rest & 3;         // 4 col tiles of 256
    int bm   = rest >> 2;        // up to 64 row tiles of 128
    int cnte = cnt[e];
    if (cnte == 0 || bm * BM2 >= cnte) return;

    // 3 ring slots x (A[128][32] 8KB + B[256][32] 16KB) = 72 KB
    __shared__ __attribute__((aligned(16))) char smem[3 * SLOT];

    int tid    = threadIdx.x;
    int lane   = tid & 63;
    int wv     = tid >> 6;        // 0..3, 2(M) x 2(N)
    int lane15 = lane & 15;
    int quad   = lane >> 4;
    int wm = (wv >> 1) * 64;      // wave row base (64 rows each)
    int wn = (wv & 1) * 128;      // wave col base (128 cols each)

    // staging addresses (16B chunk XOR-swizzle on the GLOBAL source; LDS
    // dest stays linear as required by global_load_lds)
    int rA  = tid >> 2;                         // 0..63
    int csw = (tid & 3) ^ ((rA >> 1) & 3);      // same for rA+64k (64%8==0)
    const int* epe = entries + e * T_TOK;
    int r0 = bm * BM2 + rA;
    int r1 = r0 + 64;
    int c0 = r0 < cnte ? r0 : cnte - 1;
    int c1 = r1 < cnte ? r1 : cnte - 1;
    int tok0 = epe[c0] >> 1;
    int tok1 = epe[c1] >> 1;
    const ushort_t* gA0 = xb + (size_t)tok0 * D_IN + csw * 8;
    const ushort_t* gA1 = xb + (size_t)tok1 * D_IN + csw * 8;
    const ushort_t* WB  = Webt + (size_t)e * D_IN * D_OUT + csw * 8;
    const ushort_t* gB0 = WB + (size_t)(bn * BN2 + rA) * D_IN;
    const ushort_t* gB1 = WB + (size_t)(bn * BN2 + rA + 64) * D_IN;
    const ushort_t* gB2 = WB + (size_t)(bn * BN2 + rA + 128) * D_IN;
    const ushort_t* gB3 = WB + (size_t)(bn * BN2 + rA + 192) * D_IN;
    int wvOff = wv * 1024;

    // fragment read offsets (mirror the XOR swizzle); boff includes B base
    int aoff[4], boff[8];
#pragma unroll
    for (int mi = 0; mi < 4; ++mi) {
        int m = wm + mi * 16 + lane15;
        aoff[mi] = m * 64 + (quad ^ ((m >> 1) & 3)) * 16;
    }
#pragma unroll
    for (int ni = 0; ni < 8; ++ni) {
        int n = wn + ni * 16 + lane15;
        boff[ni] = 8192 + n * 64 + (quad ^ ((n >> 1) & 3)) * 16;
    }

    f4v acc[4][8];
#pragma unroll
    for (int mi = 0; mi < 4; ++mi)
#pragma unroll
        for (int ni = 0; ni < 8; ++ni)
            acc[mi][ni] = (f4v){0.f, 0.f, 0.f, 0.f};

#define STAGE(ti)                                                          \
    do {                                                                   \
        char* _b = smem + ((ti) % 3) * SLOT;                               \
        int _k = (ti) * BK2;                                               \
        async_copy16(gA0 + _k, _b + wvOff);                                \
        async_copy16(gA1 + _k, _b + 4096 + wvOff);                         \
        async_copy16(gB0 + _k, _b + 8192 + wvOff);                         \
        async_copy16(gB1 + _k, _b + 12288 + wvOff);                        \
        async_copy16(gB2 + _k, _b + 16384 + wvOff);                        \
        async_copy16(gB3 + _k, _b + 20480 + wvOff);                        \
    } while (0)

#define COMPUTE(ti)                                                        \
    do {                                                                   \
        const char* ab = smem + ((ti) % 3) * SLOT;                         \
        s8v a[4], b[8];                                                    \
        _Pragma("unroll")                                                  \
        for (int mi = 0; mi < 4; ++mi) a[mi] = *(const s8v*)(ab + aoff[mi]); \
        _Pragma("unroll")                                                  \
        for (int ni = 0; ni < 8; ++ni) b[ni] = *(const s8v*)(ab + boff[ni]); \
        _Pragma("unroll")                                                  \
        for (int mi = 0; mi < 4; ++mi)                                     \
            _Pragma("unroll")                                              \
            for (int ni = 0; ni < 8; ++ni)                                 \
                acc[mi][ni] = __builtin_amdgcn_mfma_f32_16x16x32_bf16(     \
                    a[mi], b[ni], acc[mi][ni], 0, 0, 0);                   \
    } while (0)

    // prologue: tiles 0 and 1 in flight (12 loads/wave)
    STAGE(0);
    STAGE(1);

    // main loop: wait tile i ready (keep tile i+1's 6 loads in flight),
    // prefetch tile i+2, compute tile i.
#pragma unroll 3
    for (int i = 0; i < 30; ++i) {
        PIPE_BARRIER_VM6();
        STAGE(i + 2);
        COMPUTE(i);
    }
    PIPE_BARRIER_VM6();   // tile 30 ready (31 still in flight)
    COMPUTE(30);
    PIPE_BARRIER_VM0();   // tile 31 ready
    COMPUTE(31);

    // ---- epilogue: scale+bias, stage tile in LDS (aliased), coalesced store
    __syncthreads();   // all ds_reads done before smem is reused as ot
    ushort_t (*ot)[268] = (ushort_t(*)[268])smem;  // 128 x 268 x 2B = 67 KB
    float bev[8];
#pragma unroll
    for (int ni = 0; ni < 8; ++ni)
        bev[ni] = be[e * D_OUT + bn * BN2 + wn + ni * 16 + lane15];

#pragma unroll
    for (int mi = 0; mi < 4; ++mi) {
#pragma unroll
        for (int r = 0; r < 4; ++r) {
            int lrow = wm + mi * 16 + quad * 4 + r;
            int grow = bm * BM2 + lrow;
            int cr   = grow < cnte ? grow : cnte - 1;
            float w  = grow < cnte ? wslot[epe[cr]] : 0.f;
#pragma unroll
            for (int ni = 0; ni < 8; ++ni)
                ot[lrow][wn + ni * 16 + lane15] =
                    f2bf(w * (acc[mi][ni][r] + bev[ni]));
        }
    }
    __syncthreads();

    {
        int row  = tid >> 1;          // 0..127
        int half = tid & 1;           // 128-col halves
        int grow = bm * BM2 + row;
        if (grow < cnte) {
            int ent = epe[grow];
            ushort_t* dst = yslot + (size_t)ent * D_OUT + bn * BN2 + half * 128;
            const ushort_t* srcr = &ot[row][half * 128];
#pragma unroll
            for (int j = 0; j < 16; ++j)
                *(s8v*)(dst + j * 8) = *(const s8v*)(srcr + j * 8);
        }
    }
}

// ------- combine (+ fused aux): y[t] = ys[2t] + ys[2t+1] --------------------
__global__ void combine_kernel(const ushort_t* __restrict__ yslot,
                               const float* __restrict__ psum,
                               const int* __restrict__ cnt,
                               float* __restrict__ out) {
    size_t i = ((size_t)blockIdx.x * 256 + threadIdx.x) * 4;
    size_t t = i >> 10;
    size_t h = i & 1023;
    const ushort_t* p0 = yslot + (2 * t) * D_OUT + h;
    ushort4 a = *(const ushort4*)p0;
    ushort4 b = *(const ushort4*)(p0 + D_OUT);
    float4 o;
    o.x = bf2f(a.x) + bf2f(b.x);
    o.y = bf2f(a.y) + bf2f(b.y);
    o.z = bf2f(a.z) + bf2f(b.z);
    o.w = bf2f(a.w) + bf2f(b.w);
    *(float4*)(out + i) = o;
    if (i == 0) {
        float s = 0.f;
#pragma unroll
        for (int e = 0; e < N_EXP; ++e)
            s += (psum[e] / (float)T_TOK) * ((float)cnt[e] / (float)(T_TOK * 2));
        out[(size_t)T_TOK * D_OUT] = (float)N_EXP * s;
    }
}

extern "C" void kernel_launch(void* const* d_in, const int* in_sizes, int n_in,
                              void* d_out, int out_size, void* d_ws, size_t ws_size,
                              hipStream_t stream) {
    const float* x  = (const float*)d_in[0];
    const float* Wr = (const float*)d_in[1];
    const float* br = (const float*)d_in[2];
    const float* We = (const float*)d_in[3];
    const float* be = (const float*)d_in[4];
    float* out = (float*)d_out;

    char* ws = (char*)d_ws;
    ushort_t* xb      = (ushort_t*)(ws);                    // 16 MiB
    ushort_t* Webt    = (ushort_t*)(ws + 16777216);         // 16 MiB
    ushort_t* yslot   = (ushort_t*)(ws + 33554432);         // 32 MiB (bf16)
    int*      entries = (int*)(ws + 67108864);              // 256 KiB
    float*    wslot   = (float*)(ws + 67371008);            // 64 KiB
    float*    logits  = (float*)(ws + 67436544);            // 256 KiB
    float*    psum    = (float*)(ws + 67698688);            // 32 B
    int*      cnt     = (int*)(ws + 67698720);              // 32 B

    hipLaunchKernelGGL(prep_kernel, dim3(T_TOK + 2048), dim3(256), 0, stream,
                       x, Wr, br, We, xb, Webt, logits, cnt, psum);
    hipLaunchKernelGGL(route_kernel, dim3(32), dim3(256), 0, stream,
                       logits, wslot, entries, cnt, psum);
    hipLaunchKernelGGL(moe_gemm, dim3(2048), dim3(256), 0, stream,
                       xb, Webt, be, entries, cnt, wslot, yslot);
    hipLaunchKernelGGL(combine_kernel, dim3(8192), dim3(256), 0, stream,
                       yslot, psum, cnt, out);
}